// Round 4
// baseline (294.690 us; speedup 1.0000x reference)
//
#include <hip/hip_runtime.h>

#define THREADS 512
#define BLOCKS  1024   // 1024*512 = 524288 threads = 8192 waves = 32/CU: full residency
#define ITERS   16     // per-block tile: 16*512 float4 = 8192 float4 = 128 KB per array
#define UNROLL  4

typedef float f32x4 __attribute__((ext_vector_type(4)));

// Ticket counter for last-block detection. Zero-initialized at module load;
// the last block resets it to 0 every execution -> safe across graph replays
// and rocprof counter-group replays (each execution is self-cleaning).
__device__ unsigned int g_ticket = 0;

__global__ __launch_bounds__(THREADS) void dot_fused_kernel(
        const f32x4* __restrict__ a,
        const f32x4* __restrict__ b,
        float* __restrict__ partial,
        float* __restrict__ out,
        float inv_n) {
    // Block-contiguous tile: block owns [blockIdx*8192, (blockIdx+1)*8192) float4s.
    // R0 body verbatim: all-nontemporal loads measured fastest (~3.7 TB/s read,
    // the empirical read-path ceiling; R1 plain=2.7, R3 hybrid regressed).
    const int base = blockIdx.x * (ITERS * THREADS) + threadIdx.x;

    f32x4 acc0 = (f32x4)0.f, acc1 = (f32x4)0.f, acc2 = (f32x4)0.f, acc3 = (f32x4)0.f;

    #pragma unroll
    for (int i = 0; i < ITERS; i += UNROLL) {
        const int i0 = base + (i + 0) * THREADS;
        const int i1 = base + (i + 1) * THREADS;
        const int i2 = base + (i + 2) * THREADS;
        const int i3 = base + (i + 3) * THREADS;
        f32x4 a0 = __builtin_nontemporal_load(a + i0);
        f32x4 b0 = __builtin_nontemporal_load(b + i0);
        f32x4 a1 = __builtin_nontemporal_load(a + i1);
        f32x4 b1 = __builtin_nontemporal_load(b + i1);
        f32x4 a2 = __builtin_nontemporal_load(a + i2);
        f32x4 b2 = __builtin_nontemporal_load(b + i2);
        f32x4 a3 = __builtin_nontemporal_load(a + i3);
        f32x4 b3 = __builtin_nontemporal_load(b + i3);
        acc0 += a0 * b0;
        acc1 += a1 * b1;
        acc2 += a2 * b2;
        acc3 += a3 * b3;
    }

    f32x4 accv = (acc0 + acc1) + (acc2 + acc3);
    float s = (accv.x + accv.y) + (accv.z + accv.w);

    // wave-64 shuffle reduction
    #pragma unroll
    for (int off = 32; off > 0; off >>= 1)
        s += __shfl_down(s, off, 64);

    __shared__ float smem[THREADS / 64];
    __shared__ unsigned int ticket;
    const int lane = threadIdx.x & 63;
    const int wave = threadIdx.x >> 6;
    if (lane == 0) smem[wave] = s;
    __syncthreads();

    if (threadIdx.x == 0) {
        float t = 0.f;
        #pragma unroll
        for (int w = 0; w < THREADS / 64; ++w) t += smem[w];
        // Agent-scope store: per-XCD L2s are not coherent for plain accesses,
        // and the poison fill may have left stale ws lines in other XCDs' L2.
        __hip_atomic_store(&partial[blockIdx.x], t, __ATOMIC_RELAXED,
                           __HIP_MEMORY_SCOPE_AGENT);
        // acq_rel RMW: orders our partial store before the ticket increment,
        // and gives the last block acquire over all earlier blocks' stores.
        ticket = __hip_atomic_fetch_add(&g_ticket, 1u, __ATOMIC_ACQ_REL,
                                        __HIP_MEMORY_SCOPE_AGENT);
    }
    __syncthreads();

    if (ticket == BLOCKS - 1) {
        // We are the last block: all 1024 partials are visible (acq_rel chain).
        float r = __hip_atomic_load(&partial[threadIdx.x], __ATOMIC_RELAXED,
                                    __HIP_MEMORY_SCOPE_AGENT)
                + __hip_atomic_load(&partial[threadIdx.x + THREADS], __ATOMIC_RELAXED,
                                    __HIP_MEMORY_SCOPE_AGENT);

        #pragma unroll
        for (int off = 32; off > 0; off >>= 1)
            r += __shfl_down(r, off, 64);

        if (lane == 0) smem[wave] = r;   // safe: all threads passed the sync above
        __syncthreads();

        if (threadIdx.x == 0) {
            float t = 0.f;
            #pragma unroll
            for (int w = 0; w < THREADS / 64; ++w) t += smem[w];
            out[0] = 1.0f - t * inv_n;
            // Reset for the next replay (we are provably the last arriver).
            __hip_atomic_store(&g_ticket, 0u, __ATOMIC_RELAXED,
                               __HIP_MEMORY_SCOPE_AGENT);
        }
    }
}

extern "C" void kernel_launch(void* const* d_in, const int* in_sizes, int n_in,
                              void* d_out, int out_size, void* d_ws, size_t ws_size,
                              hipStream_t stream) {
    const float* feats  = (const float*)d_in[0];
    const float* warped = (const float*)d_in[1];
    float* out = (float*)d_out;
    float* ws  = (float*)d_ws;

    const float inv_n = 1.0f / 65536.0f;   // N fixed by the reference

    dot_fused_kernel<<<BLOCKS, THREADS, 0, stream>>>(
        (const f32x4*)feats, (const f32x4*)warped, ws, out, inv_n);
}

// Round 5
// 249.333 us; speedup vs baseline: 1.1819x; 1.1819x over previous
//
#include <hip/hip_runtime.h>

#define THREADS 512
#define BLOCKS  1024   // 1024*512 = 524288 threads = 8192 waves = 32/CU: full residency
#define ITERS   16     // per-block tile: 16*512 float4 = 8192 float4 = 128 KB per array
#define UNROLL  4

typedef float f32x4 __attribute__((ext_vector_type(4)));

// R0 configuration, reverted verbatim — measured best (248.4 us total).
// Session evidence:
//   R1: allocating loads     -> +28 us (L3 thrash + allocate path)
//   R2: deep SW pipeline     -> null   (not issue/MLP-bound)
//   R3: hybrid nt/plain      -> +11 us (mixed stream degraded)
//   R4: fused single-kernel  -> +46 us (same-address agent-scope RMW serialized)
// Dot kernel runs <=77 us for 268 MB (~3.5 TB/s read-only) -- at/above every
// read-path measurement on this platform (m13 copy read component ~3.15 TB/s).
// Limiter is per-CU outstanding-miss x latency, not HBM BW (R4: FETCH half
// L3-served, HBM 1.45 TB/s, VALUBusy 2%, time unchanged).
__global__ __launch_bounds__(THREADS) void dot_partial_kernel(
        const f32x4* __restrict__ a,
        const f32x4* __restrict__ b,
        float* __restrict__ partial) {
    // Block-contiguous tile: block owns [blockIdx*8192, (blockIdx+1)*8192) float4s.
    const int base = blockIdx.x * (ITERS * THREADS) + threadIdx.x;

    f32x4 acc0 = (f32x4)0.f, acc1 = (f32x4)0.f, acc2 = (f32x4)0.f, acc3 = (f32x4)0.f;

    #pragma unroll
    for (int i = 0; i < ITERS; i += UNROLL) {
        const int i0 = base + (i + 0) * THREADS;
        const int i1 = base + (i + 1) * THREADS;
        const int i2 = base + (i + 2) * THREADS;
        const int i3 = base + (i + 3) * THREADS;
        f32x4 a0 = __builtin_nontemporal_load(a + i0);
        f32x4 b0 = __builtin_nontemporal_load(b + i0);
        f32x4 a1 = __builtin_nontemporal_load(a + i1);
        f32x4 b1 = __builtin_nontemporal_load(b + i1);
        f32x4 a2 = __builtin_nontemporal_load(a + i2);
        f32x4 b2 = __builtin_nontemporal_load(b + i2);
        f32x4 a3 = __builtin_nontemporal_load(a + i3);
        f32x4 b3 = __builtin_nontemporal_load(b + i3);
        acc0 += a0 * b0;
        acc1 += a1 * b1;
        acc2 += a2 * b2;
        acc3 += a3 * b3;
    }

    f32x4 accv = (acc0 + acc1) + (acc2 + acc3);
    float s = (accv.x + accv.y) + (accv.z + accv.w);

    // wave-64 shuffle reduction
    #pragma unroll
    for (int off = 32; off > 0; off >>= 1)
        s += __shfl_down(s, off, 64);

    __shared__ float smem[THREADS / 64];
    const int lane = threadIdx.x & 63;
    const int wave = threadIdx.x >> 6;
    if (lane == 0) smem[wave] = s;
    __syncthreads();

    if (threadIdx.x == 0) {
        float t = 0.f;
        #pragma unroll
        for (int w = 0; w < THREADS / 64; ++w) t += smem[w];
        partial[blockIdx.x] = t;
    }
}

__global__ __launch_bounds__(256) void final_reduce_kernel(
        const float* __restrict__ partial,
        float* __restrict__ out,
        int np, float inv_n) {
    float s = 0.f;
    for (int i = threadIdx.x; i < np; i += 256) s += partial[i];

    #pragma unroll
    for (int off = 32; off > 0; off >>= 1)
        s += __shfl_down(s, off, 64);

    __shared__ float smem[4];
    const int lane = threadIdx.x & 63;
    const int wave = threadIdx.x >> 6;
    if (lane == 0) smem[wave] = s;
    __syncthreads();

    if (threadIdx.x == 0) {
        float t = 0.f;
        #pragma unroll
        for (int w = 0; w < 4; ++w) t += smem[w];
        out[0] = 1.0f - t * inv_n;
    }
}

extern "C" void kernel_launch(void* const* d_in, const int* in_sizes, int n_in,
                              void* d_out, int out_size, void* d_ws, size_t ws_size,
                              hipStream_t stream) {
    const float* feats  = (const float*)d_in[0];
    const float* warped = (const float*)d_in[1];
    float* out = (float*)d_out;
    float* ws  = (float*)d_ws;

    const float inv_n = 1.0f / 65536.0f;   // N fixed by the reference

    dot_partial_kernel<<<BLOCKS, THREADS, 0, stream>>>(
        (const f32x4*)feats, (const f32x4*)warped, ws);
    final_reduce_kernel<<<1, 256, 0, stream>>>(ws, out, BLOCKS, inv_n);
}